// Round 2
// baseline (767.801 us; speedup 1.0000x reference)
//
#include <hip/hip_runtime.h>

// VQ eval: x[131072,64] fp32, codebook w[1024,64] fp32.
// Outputs concat: x_q (8388608 f32) | loss (1 f32) | indices (131072 f32).
//
// Strategy: the np reference computes distances = x_norm + e_norm - 2*x@w.T in
// fp32. Values ~64 are quantized at ulp(64)=7.6e-6 -> ties resolved by
// np.argmin first-index. K1 does a fast fp32 score pass with top-2 margin;
// tokens with gap < MARGIN (covers 2*ulp(64)+eps) get flagged (sign bit in the
// index slot) and K2 recomputes the np-replicated quantized score exactly:
//   C   = sequential-k fp32 FMA dot   (replicates BLAS sgemm microkernel)
//   T   = fl32(xn + en)               (xn common-mode: shift-invariant, fp64 ok)
//   d   = fl32(T - 2*C)
// with global first-index tie-break. No d_ws usage at all (robustness).

#define N_TOK   131072
#define DIM     64
#define KCODES  1024
#define CHUNK   128
#define K1_THREADS 128
#define MARGIN  3e-5f
#define LOSS_POS ((size_t)8388608)   // N_TOK*DIM
#define FLAG_BITU 0x80000000u

// ------------------------------------------------- K1: fp32 argmin with top-2
__global__ __launch_bounds__(K1_THREADS) void k_argmin(
    const float* __restrict__ x, const float* __restrict__ w,
    int* __restrict__ idx_out)
{
    __shared__ float4 scode4[CHUNK * (DIM / 4)];   // 32 KB
    __shared__ float  se[CHUNK];
    const float* scode = (const float*)scode4;

    const int t    = threadIdx.x;
    const int tok0 = blockIdx.x * (K1_THREADS * 2) + t;
    const int tok1 = tok0 + K1_THREADS;

    float4 xv0[DIM / 4], xv1[DIM / 4];
    const float4* xp0 = (const float4*)(x + (size_t)tok0 * DIM);
    const float4* xp1 = (const float4*)(x + (size_t)tok1 * DIM);
#pragma unroll
    for (int k = 0; k < DIM / 4; ++k) { xv0[k] = xp0[k]; xv1[k] = xp1[k]; }

    float min1_0 = 3.4e38f, min2_0 = 3.4e38f;
    float min1_1 = 3.4e38f, min2_1 = 3.4e38f;
    int   id0 = 0, id1 = 0;

    for (int cb = 0; cb < KCODES; cb += CHUNK) {
        __syncthreads();
        const float4* wp = (const float4*)(w + (size_t)cb * DIM);
#pragma unroll
        for (int i = 0; i < (CHUNK * DIM / 4) / K1_THREADS; ++i)
            scode4[t + i * K1_THREADS] = wp[t + i * K1_THREADS];
        __syncthreads();
        // ||e||^2 for code cb+t from LDS; skewed k order -> 2-way conflicts (free)
        {
            double en = 0.0;
            const int base = t * DIM;
            for (int kk = 0; kk < DIM; ++kk) {
                int k = (kk + 2 * t) & (DIM - 1);
                float c = scode[base + k];
                en += (double)c * c;
            }
            se[t] = (float)en;
        }
        __syncthreads();

        for (int j = 0; j < CHUNK; ++j) {
            float4 d0 = {0.f, 0.f, 0.f, 0.f};
            float4 d1 = {0.f, 0.f, 0.f, 0.f};
#pragma unroll
            for (int k = 0; k < DIM / 4; ++k) {
                float4 c = scode4[j * (DIM / 4) + k];
                d0.x += c.x * xv0[k].x; d0.y += c.y * xv0[k].y;
                d0.z += c.z * xv0[k].z; d0.w += c.w * xv0[k].w;
                d1.x += c.x * xv1[k].x; d1.y += c.y * xv1[k].y;
                d1.z += c.z * xv1[k].z; d1.w += c.w * xv1[k].w;
            }
            float dot0 = (d0.x + d0.y) + (d0.z + d0.w);
            float dot1 = (d1.x + d1.y) + (d1.z + d1.w);
            float en = se[j];
            float s0 = en - 2.0f * dot0;
            float s1 = en - 2.0f * dot1;
            int   jg = cb + j;
            if (s0 < min1_0)      { min2_0 = min1_0; min1_0 = s0; id0 = jg; }
            else if (s0 < min2_0) { min2_0 = s0; }
            if (s1 < min1_1)      { min2_1 = min1_1; min1_1 = s1; id1 = jg; }
            else if (s1 < min2_1) { min2_1 = s1; }
        }
    }

    unsigned f0 = (min2_0 - min1_0 < MARGIN) ? FLAG_BITU : 0u;
    unsigned f1 = (min2_1 - min1_1 < MARGIN) ? FLAG_BITU : 0u;
    idx_out[tok0] = (int)((unsigned)id0 | f0);
    idx_out[tok1] = (int)((unsigned)id1 | f1);
}

// -------------------- K2: np-fp32-replicated rescan of flagged tokens (no ws)
__global__ __launch_bounds__(256) void k_recheck(
    const float* __restrict__ x, const float* __restrict__ w,
    int* __restrict__ idx)
{
    __shared__ int   nflag;
    __shared__ int   flist[256];
    __shared__ float xf[DIM];
    __shared__ float rd[256];
    __shared__ int   rj[256];

    const int tid = threadIdx.x;
    const int tok = blockIdx.x * 256 + tid;
    if (tid == 0) nflag = 0;
    __syncthreads();
    int v = idx[tok];
    if ((unsigned)v & FLAG_BITU) { int p = atomicAdd(&nflag, 1); flist[p] = tok; }
    __syncthreads();
    const int nf = nflag;

    for (int f = 0; f < nf; ++f) {
        const int ft = flist[f];
        if (tid < DIM) xf[tid] = x[(size_t)ft * DIM + tid];
        __syncthreads();

        // xn: common-mode across all codes -> rounding-grid shift-invariant;
        // fp64 accumulate then round is equivalent to numpy's pairwise here.
        double xnd = 0.0;
        for (int k = 0; k < DIM; ++k) { double xv = (double)xf[k]; xnd += xv * xv; }
        const float xn = (float)xnd;

        float dbest = 3.4e38f; int jbest = 0;
#pragma unroll
        for (int jj = 0; jj < KCODES / 256; ++jj) {
            const int j = tid + jj * 256;
            const float* wr = w + (size_t)j * DIM;
            double end = 0.0;
            float  c   = 0.0f;   // sequential-k fp32 FMA == BLAS sgemm microkernel
            for (int k = 0; k < DIM; ++k) {
                float wv = wr[k];
                end += (double)wv * wv;           // en error ~1e-11 << ulp grid
                c = __fmaf_rn(xf[k], wv, c);
            }
            float T = __fadd_rn(xn, (float)end);
            float d = __fsub_rn(T, __fmul_rn(2.0f, c));
            if (d < dbest) { dbest = d; jbest = j; }   // strict <: first index
        }
        rd[tid] = dbest; rj[tid] = jbest;
        __syncthreads();
        for (int off = 128; off > 0; off >>= 1) {
            if (tid < off) {
                float od = rd[tid + off]; int oj = rj[tid + off];
                if (od < rd[tid] || (od == rd[tid] && oj < rj[tid])) {
                    rd[tid] = od; rj[tid] = oj;
                }
            }
            __syncthreads();
        }
        if (tid == 0) idx[ft] = rj[0];   // flag cleared
        __syncthreads();
    }
}

// ------------------------------ k_zero: init the loss accumulator slot in out
__global__ void k_zero(float* __restrict__ out) { out[LOSS_POS] = 0.0f; }

// ------------------------- K3: gather x_q, write it out, accumulate loss sum
__global__ __launch_bounds__(256) void k_gather(
    const float* __restrict__ x, const float* __restrict__ w,
    const int* __restrict__ idx, float* __restrict__ out)
{
    const float4* x4 = (const float4*)x;
    const float4* w4 = (const float4*)w;
    float4*       o4 = (float4*)out;
    const int total4 = N_TOK * (DIM / 4);
    const int stride = gridDim.x * blockDim.x;
    double acc = 0.0;
    for (int i = blockIdx.x * blockDim.x + threadIdx.x; i < total4; i += stride) {
        int tok = i >> 4, c = i & 15;
        int id  = idx[tok];
        float4 xv = x4[i];
        float4 wv = w4[(size_t)id * (DIM / 4) + c];
        o4[i] = wv;
        float dx = xv.x - wv.x, dy = xv.y - wv.y, dz = xv.z - wv.z, dw = xv.w - wv.w;
        acc += (double)dx * dx + (double)dy * dy + (double)dz * dz + (double)dw * dw;
    }
    __shared__ double r[256];
    r[threadIdx.x] = acc;
    __syncthreads();
    for (int off = 128; off > 0; off >>= 1) {
        if (threadIdx.x < off) r[threadIdx.x] += r[threadIdx.x + off];
        __syncthreads();
    }
    if (threadIdx.x == 0) unsafeAtomicAdd(out + LOSS_POS, (float)r[0]);
}

// ---------------- K4: indices int->float in place + loss scale
__global__ __launch_bounds__(256) void k_finalize(float* __restrict__ out)
{
    int t = blockIdx.x * blockDim.x + threadIdx.x;
    float* oidx = out + LOSS_POS + 1;
    if (t < N_TOK) {
        int v = ((const int*)oidx)[t];
        oidx[t] = (float)v;
    }
    if (t == 0) {
        out[LOSS_POS] = out[LOSS_POS] * 1.25f / 8388608.0f;
    }
}

extern "C" void kernel_launch(void* const* d_in, const int* in_sizes, int n_in,
                              void* d_out, int out_size, void* d_ws, size_t ws_size,
                              hipStream_t stream) {
    const float* x = (const float*)d_in[0];
    const float* w = (const float*)d_in[1];
    float* out = (float*)d_out;
    int* idx_out = (int*)(out + LOSS_POS + 1);   // staged as int bits until K4

    k_zero<<<1, 1, 0, stream>>>(out);
    k_argmin<<<N_TOK / (K1_THREADS * 2), K1_THREADS, 0, stream>>>(x, w, idx_out);
    k_recheck<<<N_TOK / 256, 256, 0, stream>>>(x, w, idx_out);
    k_gather<<<2048, 256, 0, stream>>>(x, w, idx_out, out);
    k_finalize<<<(N_TOK + 255) / 256, 256, 0, stream>>>(out);
}

// Round 3
// 395.666 us; speedup vs baseline: 1.9405x; 1.9405x over previous
//
#include <hip/hip_runtime.h>

// VQ eval: x[131072,64] fp32, codebook w[1024,64] fp32.
// Outputs concat: x_q (8388608 f32) | loss (1 f32) | indices (131072 f32).
//
// K1 = register-tiled fp32 GEMM (scores = ||e||^2 - 2 x.e) with fused top-2
// argmin epilogue. Tokens with top-2 gap < MARGIN are flagged (sign bit) and
// K2 re-resolves them with an np-fp32-replicated exact rescan (sequential-k
// fp32 FMA dot == BLAS sgemm microkernel, quantized combine, first-index
// tie-break). No d_ws usage (robustness to unknown ws_size).

#define N_TOK   131072
#define DIM     64
#define KCODES  1024
#define MARGIN  3e-5f
#define LOSS_POS ((size_t)8388608)   // N_TOK*DIM
#define FLAG_BITU 0x80000000u

#define TM 128        // tokens per block
#define TC 128        // codes per LDS chunk
#define THREADS 256   // 16 tx * 16 ty

// LDS layout (floats):
//  XS(k,t) = smem[k*128 + t]            k in [0,64), t in [0,128)   (32 KB)
//  WS(k,c) = smem[8192 + k*128 + c]                                  (32 KB)
//  EN(c)   = smem[16384 + c]                                         (512 B)
//  merge arrays alias smem[0..6144) after the last chunk.

// --------------------------------------------- K1: tiled GEMM + top-2 argmin
__global__ __launch_bounds__(THREADS, 2) void k_argmin(
    const float* __restrict__ x, const float* __restrict__ w,
    int* __restrict__ idx_out)
{
    __shared__ float smem[16512];

    const int tid = threadIdx.x;
    const int tx  = tid & 15;
    const int ty  = tid >> 4;
    const int tokBase = blockIdx.x * TM;

    // ---- stage X tile transposed: XS[k][tok], 2-way (free) LDS write aliasing
    {
        const int t    = tid >> 1;
        const int half = tid & 1;
        const float4* xr = (const float4*)(x + (size_t)(tokBase + t) * DIM + half * 32);
#pragma unroll
        for (int q = 0; q < 8; ++q) {
            float4 v = xr[q];
            int k0 = half * 32 + q * 4;
            smem[(k0 + 0) * 128 + t] = v.x;
            smem[(k0 + 1) * 128 + t] = v.y;
            smem[(k0 + 2) * 128 + t] = v.z;
            smem[(k0 + 3) * 128 + t] = v.w;
        }
    }

    float m1[8], m2[8];
    int   mid[8];
#pragma unroll
    for (int i = 0; i < 8; ++i) { m1[i] = 3.4e38f; m2[i] = 3.4e38f; mid[i] = 0; }

    for (int cb = 0; cb < KCODES; cb += TC) {
        __syncthreads();   // prior epilogue readers done before WS/EN overwrite
        // ---- stage W chunk transposed: WS[k][code]
        {
            const int c    = tid >> 1;
            const int half = tid & 1;
            const float4* wr = (const float4*)(w + (size_t)(cb + c) * DIM + half * 32);
#pragma unroll
            for (int q = 0; q < 8; ++q) {
                float4 v = wr[q];
                int k0 = half * 32 + q * 4;
                smem[8192 + (k0 + 0) * 128 + c] = v.x;
                smem[8192 + (k0 + 1) * 128 + c] = v.y;
                smem[8192 + (k0 + 2) * 128 + c] = v.z;
                smem[8192 + (k0 + 3) * 128 + c] = v.w;
            }
        }
        __syncthreads();

        // ---- ||e||^2 for this chunk (threads 0..127; 2-way LDS reads, free)
        if (tid < 128) {
            float s = 0.f;
            for (int k = 0; k < 64; ++k) {
                float v = smem[8192 + k * 128 + tid];
                s += v * v;
            }
            smem[16384 + tid] = s;
        }

        // ---- 8x8 register-tile GEMM over k
        float acc[8][8];
#pragma unroll
        for (int i = 0; i < 8; ++i)
#pragma unroll
            for (int j = 0; j < 8; ++j) acc[i][j] = 0.f;

#pragma unroll 4
        for (int k = 0; k < 64; ++k) {
            const float4 a0 = *(const float4*)&smem[k * 128 + ty * 8];
            const float4 a1 = *(const float4*)&smem[k * 128 + ty * 8 + 4];
            const float4 b0 = *(const float4*)&smem[8192 + k * 128 + tx * 4];
            const float4 b1 = *(const float4*)&smem[8192 + k * 128 + 64 + tx * 4];
            const float a[8] = {a0.x, a0.y, a0.z, a0.w, a1.x, a1.y, a1.z, a1.w};
            const float b[8] = {b0.x, b0.y, b0.z, b0.w, b1.x, b1.y, b1.z, b1.w};
#pragma unroll
            for (int i = 0; i < 8; ++i)
#pragma unroll
                for (int j = 0; j < 8; ++j)
                    acc[i][j] += a[i] * b[j];
        }
        __syncthreads();   // en visible to all; k-loop reads done before restage

        // ---- fused top-2 epilogue (codes scanned in ascending global index)
#pragma unroll
        for (int j = 0; j < 8; ++j) {
            const int cl = (j < 4) ? (tx * 4 + j) : (64 + tx * 4 + (j - 4));
            const float en = smem[16384 + cl];
            const int   jg = cb + cl;
#pragma unroll
            for (int i = 0; i < 8; ++i) {
                float s = en - 2.0f * acc[i][j];
                if (s < m1[i])      { m2[i] = m1[i]; m1[i] = s; mid[i] = jg; }
                else if (s < m2[i]) { m2[i] = s; }
            }
        }
    }

    __syncthreads();
    // ---- cross-thread merge over tx (alias smem; X/W no longer needed)
    float* M1 = smem;
    float* M2 = smem + 2048;
    int*   MI = (int*)(smem + 4096);
#pragma unroll
    for (int i = 0; i < 8; ++i) {
        int t = ty * 8 + i;
        M1[t * 16 + tx] = m1[i];
        M2[t * 16 + tx] = m2[i];
        MI[t * 16 + tx] = mid[i];
    }
    __syncthreads();
    for (int s2 = 8; s2 > 0; s2 >>= 1) {
        if (tx < s2) {
#pragma unroll
            for (int i = 0; i < 8; ++i) {
                int e = (ty * 8 + i) * 16 + tx;
                int o = e + s2;
                float o1 = M1[o], o2 = M2[o]; int oi = MI[o];
                float c1 = M1[e], c2 = M2[e]; int ci = MI[e];
                if (o1 < c1) {
                    M1[e] = o1; MI[e] = oi;
                    M2[e] = fminf(c1, o2);
                } else if (o1 == c1) {
                    M2[e] = c1;                       // duplicate min -> gap 0 -> flagged
                    MI[e] = (oi < ci) ? oi : ci;
                } else {
                    M2[e] = fminf(c2, o1);
                }
            }
        }
        __syncthreads();
    }
    if (tx == 0) {
#pragma unroll
        for (int i = 0; i < 8; ++i) {
            int t = ty * 8 + i;
            int e = t * 16;
            unsigned flag = (M2[e] - M1[e] < MARGIN) ? FLAG_BITU : 0u;
            idx_out[tokBase + t] = (int)((unsigned)MI[e] | flag);
        }
    }
}

// -------------------- K2: np-fp32-replicated rescan of flagged tokens (no ws)
__global__ __launch_bounds__(256) void k_recheck(
    const float* __restrict__ x, const float* __restrict__ w,
    int* __restrict__ idx)
{
    __shared__ int   nflag;
    __shared__ int   flist[256];
    __shared__ float xf[DIM];
    __shared__ float rd[256];
    __shared__ int   rj[256];

    const int tid = threadIdx.x;
    const int tok = blockIdx.x * 256 + tid;
    if (tid == 0) nflag = 0;
    __syncthreads();
    int v = idx[tok];
    if ((unsigned)v & FLAG_BITU) { int p = atomicAdd(&nflag, 1); flist[p] = tok; }
    __syncthreads();
    const int nf = nflag;

    for (int f = 0; f < nf; ++f) {
        const int ft = flist[f];
        if (tid < DIM) xf[tid] = x[(size_t)ft * DIM + tid];
        __syncthreads();

        double xnd = 0.0;
        for (int k = 0; k < DIM; ++k) { double xv = (double)xf[k]; xnd += xv * xv; }
        const float xn = (float)xnd;

        float dbest = 3.4e38f; int jbest = 0;
#pragma unroll
        for (int jj = 0; jj < KCODES / 256; ++jj) {
            const int j = tid + jj * 256;
            const float* wr = w + (size_t)j * DIM;
            double end = 0.0;
            float  c   = 0.0f;   // sequential-k fp32 FMA == BLAS sgemm microkernel
            for (int k = 0; k < DIM; ++k) {
                float wv = wr[k];
                end += (double)wv * wv;
                c = __fmaf_rn(xf[k], wv, c);
            }
            float T = __fadd_rn(xn, (float)end);
            float d = __fsub_rn(T, __fmul_rn(2.0f, c));
            if (d < dbest) { dbest = d; jbest = j; }   // strict <: first index
        }
        rd[tid] = dbest; rj[tid] = jbest;
        __syncthreads();
        for (int off = 128; off > 0; off >>= 1) {
            if (tid < off) {
                float od = rd[tid + off]; int oj = rj[tid + off];
                if (od < rd[tid] || (od == rd[tid] && oj < rj[tid])) {
                    rd[tid] = od; rj[tid] = oj;
                }
            }
            __syncthreads();
        }
        if (tid == 0) idx[ft] = rj[0];   // flag cleared
        __syncthreads();
    }
}

// ------------------------------ k_zero: init the loss accumulator slot in out
__global__ void k_zero(float* __restrict__ out) { out[LOSS_POS] = 0.0f; }

// ------------------------- K3: gather x_q, write it out, accumulate loss sum
__global__ __launch_bounds__(256) void k_gather(
    const float* __restrict__ x, const float* __restrict__ w,
    const int* __restrict__ idx, float* __restrict__ out)
{
    const float4* x4 = (const float4*)x;
    const float4* w4 = (const float4*)w;
    float4*       o4 = (float4*)out;
    const int total4 = N_TOK * (DIM / 4);
    const int stride = gridDim.x * blockDim.x;
    double acc = 0.0;
    for (int i = blockIdx.x * blockDim.x + threadIdx.x; i < total4; i += stride) {
        int tok = i >> 4, c = i & 15;
        int id  = idx[tok];
        float4 xv = x4[i];
        float4 wv = w4[(size_t)id * (DIM / 4) + c];
        o4[i] = wv;
        float dx = xv.x - wv.x, dy = xv.y - wv.y, dz = xv.z - wv.z, dw = xv.w - wv.w;
        acc += (double)dx * dx + (double)dy * dy + (double)dz * dz + (double)dw * dw;
    }
    __shared__ double r[256];
    r[threadIdx.x] = acc;
    __syncthreads();
    for (int off = 128; off > 0; off >>= 1) {
        if (threadIdx.x < off) r[threadIdx.x] += r[threadIdx.x + off];
        __syncthreads();
    }
    if (threadIdx.x == 0) unsafeAtomicAdd(out + LOSS_POS, (float)r[0]);
}

// ---------------- K4: indices int->float in place + loss scale
__global__ __launch_bounds__(256) void k_finalize(float* __restrict__ out)
{
    int t = blockIdx.x * blockDim.x + threadIdx.x;
    float* oidx = out + LOSS_POS + 1;
    if (t < N_TOK) {
        int v = ((const int*)oidx)[t];
        oidx[t] = (float)v;
    }
    if (t == 0) {
        out[LOSS_POS] = out[LOSS_POS] * 1.25f / 8388608.0f;
    }
}

extern "C" void kernel_launch(void* const* d_in, const int* in_sizes, int n_in,
                              void* d_out, int out_size, void* d_ws, size_t ws_size,
                              hipStream_t stream) {
    const float* x = (const float*)d_in[0];
    const float* w = (const float*)d_in[1];
    float* out = (float*)d_out;
    int* idx_out = (int*)(out + LOSS_POS + 1);   // staged as int bits until K4

    k_zero<<<1, 1, 0, stream>>>(out);
    k_argmin<<<N_TOK / TM, THREADS, 0, stream>>>(x, w, idx_out);
    k_recheck<<<N_TOK / 256, 256, 0, stream>>>(x, w, idx_out);
    k_gather<<<2048, 256, 0, stream>>>(x, w, idx_out, out);
    k_finalize<<<(N_TOK + 255) / 256, 256, 0, stream>>>(out);
}

// Round 4
// 249.533 us; speedup vs baseline: 3.0769x; 1.5856x over previous
//
#include <hip/hip_runtime.h>

// VQ eval: x[131072,64] fp32, w[1024,64] fp32.
// out concat: x_q (8388608 f32) | loss (1 f32) | indices (131072 f32).
//
// Screen = one bf16 MFMA GEMM with K=192 via the split trick:
//   A_ext = [x_h | x_l | x_h],  B_ext = [w_h | w_h | w_l]  (bf16 RNE hi + residual)
//   dot_ext = x_h.w_h + x_l.w_h + x_h.w_l  ->  |err vs exact| ~5e-7
// score = en - 2*dot_ext; top-2 gap < MARGIN -> flag (sign bit) -> K2 re-resolves
// with the np-fp32-replicated scan (sequential-k fp32 FMA == BLAS sgemm kernel,
// quantized combine, first-index ties). No d_ws usage; w_ext/en scratch lives in
// the out buffer head (overwritten later by k_gather).

#define N_TOK   131072
#define DIM     64
#define KCODES  1024
#define MARGIN  3e-5f
#define LOSS_POS ((size_t)8388608)
#define FLAG_BITU 0x80000000u
#define EN_OFF_F 102400          // en[1024] floats at out+102400 (w_ext is 0..409600 B)

typedef __attribute__((ext_vector_type(8))) short  short8;
typedef __attribute__((ext_vector_type(4))) float  float4v;

__device__ __forceinline__ unsigned bf16rne(float f) {
    unsigned u = __float_as_uint(f);
    return (u + 0x7FFFu + ((u >> 16) & 1u)) >> 16;
}
__device__ __forceinline__ float bf16tof(unsigned h) { return __uint_as_float(h << 16); }

// ---------------- K0: build w_ext (1024 rows x 400B: [w_h|w_h|w_l] bf16 + pad) + en
__global__ __launch_bounds__(256) void k_prep(const float* __restrict__ w,
                                              float* __restrict__ out) {
    int j = blockIdx.x * 256 + threadIdx.x;           // 0..1023
    const float* wr = w + (size_t)j * DIM;
    unsigned* dst = (unsigned*)out + (size_t)j * 100; // 100 uints = 200 bf16 = 400 B
    double en = 0.0;
    for (int kk = 0; kk < 32; ++kk) {
        float v0 = wr[2 * kk], v1 = wr[2 * kk + 1];
        en += (double)v0 * v0 + (double)v1 * v1;
        unsigned h0 = bf16rne(v0), h1 = bf16rne(v1);
        float l0 = v0 - bf16tof(h0), l1 = v1 - bf16tof(h1);
        unsigned hp = h0 | (h1 << 16);
        unsigned lp = bf16rne(l0) | (bf16rne(l1) << 16);
        dst[kk] = hp; dst[32 + kk] = hp; dst[64 + kk] = lp;
    }
    dst[96] = dst[97] = dst[98] = dst[99] = 0;
    out[EN_OFF_F + j] = (float)en;
    if (j == 0) out[LOSS_POS] = 0.0f;
}

// ---------------- K1: MFMA screen, 128 tokens/block, fused top-2
__global__ __launch_bounds__(256, 2) void k_argmin(
    const float* __restrict__ x, const float* __restrict__ outsrc,
    int* __restrict__ idx_out)
{
    __shared__ __align__(16) unsigned char smem[57344];  // B:53248 | en:4096
    unsigned* smemU = (unsigned*)smem;
    float*    en_s  = (float*)(smem + 53248);

    const int tid  = threadIdx.x;
    const int lane = tid & 63;
    const int wv   = tid >> 6;          // wave: tokens [wv*32, wv*32+32)
    const int col  = lane & 15;
    const int quad = (lane >> 4) & 3;
    const int tokBase = blockIdx.x * 128;

    // ---- stage A_ext = [x_h|x_l|x_h] rows (400B stride) into smem[0..51200)
    {
        const int tok = tid >> 1, half = tid & 1;
        const float4* xr = (const float4*)(x + (size_t)(tokBase + tok) * DIM + half * 32);
        unsigned* rb = smemU + tok * 100 + half * 16;
#pragma unroll
        for (int q = 0; q < 8; ++q) {
            float4 v = xr[q];
            unsigned hx = bf16rne(v.x), hy = bf16rne(v.y);
            unsigned hz = bf16rne(v.z), hw = bf16rne(v.w);
            unsigned h01 = hx | (hy << 16), h23 = hz | (hw << 16);
            unsigned l01 = bf16rne(v.x - bf16tof(hx)) | (bf16rne(v.y - bf16tof(hy)) << 16);
            unsigned l23 = bf16rne(v.z - bf16tof(hz)) | (bf16rne(v.w - bf16tof(hw)) << 16);
            rb[2 * q] = h01;      rb[2 * q + 1] = h23;       // x_h  (k 0..63)
            rb[32 + 2 * q] = l01; rb[32 + 2 * q + 1] = l23;  // x_l  (k 64..127)
            rb[64 + 2 * q] = h01; rb[64 + 2 * q + 1] = h23;  // x_h  (k 128..191)
        }
        const float* en_g = outsrc + EN_OFF_F;
        en_s[tid] = en_g[tid];             en_s[tid + 256] = en_g[tid + 256];
        en_s[tid + 512] = en_g[tid + 512]; en_s[tid + 768] = en_g[tid + 768];
    }
    __syncthreads();

    // ---- A fragments: register-resident for the whole kernel (2 Mtiles x 6 ksteps)
    short8 afrag[2][6];
#pragma unroll
    for (int mt = 0; mt < 2; ++mt)
#pragma unroll
        for (int ks = 0; ks < 6; ++ks)
            afrag[mt][ks] = *(const short8*)(smem + (wv * 32 + mt * 16 + col) * 400
                                                  + ks * 64 + quad * 16);
    __syncthreads();   // A region now free -> reused as B staging buffer

    float m1[8], m2[8]; int mid[8];
#pragma unroll
    for (int i = 0; i < 8; ++i) { m1[i] = 3.4e38f; m2[i] = 3.4e38f; mid[i] = 0; }

    float4v acc[2][8];
#pragma unroll
    for (int mt = 0; mt < 2; ++mt)
#pragma unroll
        for (int nt = 0; nt < 8; ++nt)
            acc[mt][nt] = (float4v){0.f, 0.f, 0.f, 0.f};

    auto epi = [&](int c) {
#pragma unroll
        for (int nt = 0; nt < 8; ++nt) {
            const int jg = c * 128 + nt * 16 + col;
            const float ec = en_s[jg];
#pragma unroll
            for (int mt = 0; mt < 2; ++mt)
#pragma unroll
                for (int r = 0; r < 4; ++r) {
                    float s = fmaf(acc[mt][nt][r], -2.0f, ec);
                    const int t = mt * 4 + r;
                    if (s < m1[t])      { m2[t] = m1[t]; m1[t] = s; mid[t] = jg; }
                    else if (s < m2[t]) { m2[t] = s; }
                    acc[mt][nt][r] = 0.0f;
                }
        }
    };

    const unsigned char* wext = (const unsigned char*)outsrc;

    for (int c = 0; c < 8; ++c) {
        // issue async staging of chunk c (128 codes x 400B = 51200B, over-read to 53248)
        {
            const unsigned char* gsrc = wext + c * 51200 + tid * 16;
            unsigned char*       ldst = smem + tid * 16;
#pragma unroll
            for (int it = 0; it < 13; ++it) {
                __builtin_amdgcn_global_load_lds(
                    (const __attribute__((address_space(1))) void*)(gsrc + it * 4096),
                    (__attribute__((address_space(3))) void*)(ldst + it * 4096),
                    16, 0, 0);
            }
        }
        if (c > 0) epi(c - 1);      // overlap previous epilogue with load latency
        __syncthreads();            // drains vmcnt -> B chunk resident

#pragma unroll
        for (int ks = 0; ks < 6; ++ks) {
            short8 b[8];
#pragma unroll
            for (int nt = 0; nt < 8; ++nt)
                b[nt] = *(const short8*)(smem + (nt * 16 + col) * 400 + ks * 64 + quad * 16);
#pragma unroll
            for (int nt = 0; nt < 8; ++nt) {
                acc[0][nt] = __builtin_amdgcn_mfma_f32_16x16x32_bf16(afrag[0][ks], b[nt], acc[0][nt], 0, 0, 0);
                acc[1][nt] = __builtin_amdgcn_mfma_f32_16x16x32_bf16(afrag[1][ks], b[nt], acc[1][nt], 0, 0, 0);
            }
        }
        __syncthreads();            // all B reads done before next chunk's staging
    }
    epi(7);

    // ---- merge top-2 across the 16 C/D columns (lane bits 0..3)
#pragma unroll
    for (int m = 1; m <= 8; m <<= 1) {
#pragma unroll
        for (int t = 0; t < 8; ++t) {
            float o1 = __shfl_xor(m1[t], m, 64);
            float o2 = __shfl_xor(m2[t], m, 64);
            int   oi = __shfl_xor(mid[t], m, 64);
            if (o1 < m1[t])       { m2[t] = fminf(m1[t], o2); m1[t] = o1; mid[t] = oi; }
            else if (o1 == m1[t]) { m2[t] = m1[t]; mid[t] = min(mid[t], oi); }  // tie -> gap 0 -> flagged
            else                  { m2[t] = fminf(m2[t], o1); }
        }
    }
    if (col == 0) {
#pragma unroll
        for (int t = 0; t < 8; ++t) {
            const int mt = t >> 2, r = t & 3;
            const int tok = tokBase + wv * 32 + mt * 16 + quad * 4 + r;
            unsigned flag = (m2[t] - m1[t] < MARGIN) ? FLAG_BITU : 0u;
            idx_out[tok] = (int)((unsigned)mid[t] | flag);
        }
    }
}

// ---------------- K2: np-fp32-replicated rescan of flagged tokens (unchanged, proven)
__global__ __launch_bounds__(256) void k_recheck(
    const float* __restrict__ x, const float* __restrict__ w,
    int* __restrict__ idx)
{
    __shared__ int   nflag;
    __shared__ int   flist[256];
    __shared__ float xf[DIM];
    __shared__ float rd[256];
    __shared__ int   rj[256];

    const int tid = threadIdx.x;
    const int tok = blockIdx.x * 256 + tid;
    if (tid == 0) nflag = 0;
    __syncthreads();
    int v = idx[tok];
    if ((unsigned)v & FLAG_BITU) { int p = atomicAdd(&nflag, 1); flist[p] = tok; }
    __syncthreads();
    const int nf = nflag;

    for (int f = 0; f < nf; ++f) {
        const int ft = flist[f];
        if (tid < DIM) xf[tid] = x[(size_t)ft * DIM + tid];
        __syncthreads();

        double xnd = 0.0;
        for (int k = 0; k < DIM; ++k) { double xv = (double)xf[k]; xnd += xv * xv; }
        const float xn = (float)xnd;

        float dbest = 3.4e38f; int jbest = 0;
#pragma unroll
        for (int jj = 0; jj < KCODES / 256; ++jj) {
            const int j = tid + jj * 256;
            const float* wr = w + (size_t)j * DIM;
            double end = 0.0;
            float  c   = 0.0f;
            for (int k = 0; k < DIM; ++k) {
                float wv = wr[k];
                end += (double)wv * wv;
                c = __fmaf_rn(xf[k], wv, c);
            }
            float T = __fadd_rn(xn, (float)end);
            float d = __fsub_rn(T, __fmul_rn(2.0f, c));
            if (d < dbest) { dbest = d; jbest = j; }
        }
        rd[tid] = dbest; rj[tid] = jbest;
        __syncthreads();
        for (int off = 128; off > 0; off >>= 1) {
            if (tid < off) {
                float od = rd[tid + off]; int oj = rj[tid + off];
                if (od < rd[tid] || (od == rd[tid] && oj < rj[tid])) {
                    rd[tid] = od; rj[tid] = oj;
                }
            }
            __syncthreads();
        }
        if (tid == 0) idx[ft] = rj[0];
        __syncthreads();
    }
}

// ---------------- K3: gather x_q + loss sum + idx int->float (fused)
__global__ __launch_bounds__(256) void k_gather(
    const float* __restrict__ x, const float* __restrict__ w,
    int* __restrict__ idx, float* __restrict__ out)
{
    const float4* x4 = (const float4*)x;
    const float4* w4 = (const float4*)w;
    float4*       o4 = (float4*)out;
    float*        fidx = (float*)idx;
    const int total4 = N_TOK * (DIM / 4);
    const int stride = gridDim.x * blockDim.x;
    double acc = 0.0;
    for (int i = blockIdx.x * blockDim.x + threadIdx.x; i < total4; i += stride) {
        int tok = i >> 4, c = i & 15;
        int id  = idx[tok];
        float4 xv = x4[i];
        float4 wv = w4[(size_t)id * (DIM / 4) + c];
        o4[i] = wv;
        float dx = xv.x - wv.x, dy = xv.y - wv.y, dz = xv.z - wv.z, dw = xv.w - wv.w;
        acc += (double)dx * dx + (double)dy * dy + (double)dz * dz + (double)dw * dw;
        if ((i & 15) == 0) fidx[tok] = (float)id;   // wave-lockstep: loads precede store
    }
    __shared__ double r[256];
    r[threadIdx.x] = acc;
    __syncthreads();
    for (int off = 128; off > 0; off >>= 1) {
        if (threadIdx.x < off) r[threadIdx.x] += r[threadIdx.x + off];
        __syncthreads();
    }
    if (threadIdx.x == 0) unsafeAtomicAdd(out + LOSS_POS, (float)r[0]);
}

// ---------------- K4: loss scale only
__global__ void k_loss(float* __restrict__ out) {
    if (threadIdx.x == 0) out[LOSS_POS] = out[LOSS_POS] * 1.25f / 8388608.0f;
}

extern "C" void kernel_launch(void* const* d_in, const int* in_sizes, int n_in,
                              void* d_out, int out_size, void* d_ws, size_t ws_size,
                              hipStream_t stream) {
    const float* x = (const float*)d_in[0];
    const float* w = (const float*)d_in[1];
    float* out = (float*)d_out;
    int* idx_out = (int*)(out + LOSS_POS + 1);   // staged as int bits until k_gather

    k_prep<<<4, 256, 0, stream>>>(w, out);
    k_argmin<<<N_TOK / 128, 256, 0, stream>>>(x, out, idx_out);
    k_recheck<<<N_TOK / 256, 256, 0, stream>>>(x, w, idx_out);
    k_gather<<<2048, 256, 0, stream>>>(x, w, idx_out, out);
    k_loss<<<1, 64, 0, stream>>>(out);
}